// Round 6
// baseline (295.612 us; speedup 1.0000x reference)
//
#include <hip/hip_runtime.h>

#define D   64
#define H   8
#define DH  8
#define ED  16
#define QK_SCALE 0.35355339059327373f   // 1/sqrt(8)

__device__ __forceinline__ void fma4(float4& a, float s, const float4& w) {
    a.x += s * w.x; a.y += s * w.y; a.z += s * w.z; a.w += s * w.w;
}

// ---------------------------------------------------------------------------
// K1: node projections q,k,v,x_r ([N,64] each). q pre-scaled by 1/sqrt(8).
// ---------------------------------------------------------------------------
__global__ __launch_bounds__(256) void node_proj(
    const float* __restrict__ x,
    const float* __restrict__ Wq, const float* __restrict__ bq,
    const float* __restrict__ Wk, const float* __restrict__ bk,
    const float* __restrict__ Wv, const float* __restrict__ bv,
    const float* __restrict__ Ws, const float* __restrict__ bs,
    float* __restrict__ q, float* __restrict__ k,
    float* __restrict__ v, float* __restrict__ xr, int N)
{
    __shared__ float sW[4][D * D];          // 64 KB
    {
        const float* wsrc[4] = {Wq, Wk, Wv, Ws};
        for (int m = 0; m < 4; ++m)
            for (int t = threadIdx.x; t < D * D; t += 256)
                sW[m][t] = wsrc[m][t];
    }
    __syncthreads();

    int cg = (threadIdx.x & 15) * 4;
    float4 vbq = *(const float4*)(bq + cg);
    float4 vbk = *(const float4*)(bk + cg);
    float4 vbv = *(const float4*)(bv + cg);
    float4 vbs = *(const float4*)(bs + cg);

    #pragma unroll 1
    for (int it = 0; it < 4; ++it) {
        int node = blockIdx.x * 64 + it * 16 + (threadIdx.x >> 4);
        if (node >= N) return;

        float4 aq = {0,0,0,0}, ak = {0,0,0,0}, av = {0,0,0,0}, as_ = {0,0,0,0};
        const float* xrow = x + (size_t)node * D;

        #pragma unroll
        for (int i = 0; i < D; i += 4) {
            float4 xv = *(const float4*)(xrow + i);
            #pragma unroll
            for (int s = 0; s < 4; ++s) {
                float xs = (&xv.x)[s];
                fma4(aq, xs, *(const float4*)(&sW[0][(i + s) * D + cg]));
                fma4(ak, xs, *(const float4*)(&sW[1][(i + s) * D + cg]));
                fma4(av, xs, *(const float4*)(&sW[2][(i + s) * D + cg]));
                fma4(as_, xs, *(const float4*)(&sW[3][(i + s) * D + cg]));
            }
        }
        aq.x = (aq.x + vbq.x) * QK_SCALE;
        aq.y = (aq.y + vbq.y) * QK_SCALE;
        aq.z = (aq.z + vbq.z) * QK_SCALE;
        aq.w = (aq.w + vbq.w) * QK_SCALE;
        ak.x += vbk.x; ak.y += vbk.y; ak.z += vbk.z; ak.w += vbk.w;
        av.x += vbv.x; av.y += vbv.y; av.z += vbv.z; av.w += vbv.w;
        as_.x += vbs.x; as_.y += vbs.y; as_.z += vbs.z; as_.w += vbs.w;

        size_t o = (size_t)node * D + cg;
        *(float4*)(q  + o) = aq;
        *(float4*)(k  + o) = ak;
        *(float4*)(v  + o) = av;
        *(float4*)(xr + o) = as_;
    }
}

// ---------------------------------------------------------------------------
// K1b: per-node A[n,h,i] = sum_dh q[n,h,dh]*We[i,h*8+dh]  (q already scaled)
//      and qbe[n,h] = sum_dh q[n,h,dh]*be[h*8+dh]. Wave per node.
// ---------------------------------------------------------------------------
__global__ __launch_bounds__(256) void aproj(
    const float* __restrict__ q, const float* __restrict__ We,
    const float* __restrict__ be, float* __restrict__ A,
    float* __restrict__ qbe, int N)
{
    __shared__ float sWe[ED * D];
    __shared__ float sbe[D];
    for (int t = threadIdx.x; t < ED * D; t += 256) sWe[t] = We[t];
    if (threadIdx.x < D) sbe[threadIdx.x] = be[threadIdx.x];
    __syncthreads();

    int lane = threadIdx.x & 63;
    int nid  = blockIdx.x * 4 + (threadIdx.x >> 6);
    if (nid >= N) return;

    int h = lane >> 3, t = lane & 7;
    float qv = q[(size_t)nid * D + lane];
    float a0 = 0.f, a1 = 0.f, qb = 0.f;
    #pragma unroll
    for (int dh = 0; dh < 8; ++dh) {
        float qd = __shfl(qv, (lane & 56) + dh);
        a0 += qd * sWe[(2 * t)     * D + h * 8 + dh];
        a1 += qd * sWe[(2 * t + 1) * D + h * 8 + dh];
        qb += qd * sbe[h * 8 + dh];
    }
    ((float2*)A)[(size_t)nid * 64 + lane] = make_float2(a0, a1);
    if (t == 0) qbe[(size_t)nid * 8 + h] = qb;
}

// ---------------------------------------------------------------------------
// CSR build: histogram -> block scan (3 stages) -> scatter of (src,eid)
// ---------------------------------------------------------------------------
__global__ __launch_bounds__(256) void csr_hist(
    const int* __restrict__ ei, int* __restrict__ cnt, int E)
{
    int gid = blockIdx.x * 256 + threadIdx.x;
    if (gid < E) atomicAdd(&cnt[ei[E + gid]], 1);
}

__global__ __launch_bounds__(256) void scan_a(
    const int* __restrict__ cnt, int* __restrict__ bsum, int N)
{
    __shared__ int red[256];
    int t = threadIdx.x;
    int i = blockIdx.x * 256 + t;
    red[t] = (i < N) ? cnt[i] : 0;
    __syncthreads();
    for (int s = 128; s > 0; s >>= 1) {
        if (t < s) red[t] += red[t + s];
        __syncthreads();
    }
    if (t == 0) bsum[blockIdx.x] = red[0];
}

__global__ __launch_bounds__(256) void scan_b(int* __restrict__ bsum, int nb)
{
    __shared__ int sh[256];
    int t = threadIdx.x;
    int v = (t < nb) ? bsum[t] : 0;
    sh[t] = v;
    __syncthreads();
    for (int s = 1; s < 256; s <<= 1) {
        int a = (t >= s) ? sh[t - s] : 0;
        __syncthreads();
        sh[t] += a;
        __syncthreads();
    }
    if (t < nb) bsum[t] = sh[t] - v;   // exclusive
}

__global__ __launch_bounds__(256) void scan_c(
    const int* __restrict__ cnt, const int* __restrict__ bsum,
    int* __restrict__ row_start, int* __restrict__ cursor, int N, int E)
{
    __shared__ int sh[256];
    int t = threadIdx.x;
    int i = blockIdx.x * 256 + t;
    int v = (i < N) ? cnt[i] : 0;
    sh[t] = v;
    __syncthreads();
    for (int s = 1; s < 256; s <<= 1) {
        int a = (t >= s) ? sh[t - s] : 0;
        __syncthreads();
        sh[t] += a;
        __syncthreads();
    }
    int excl = sh[t] - v + bsum[blockIdx.x];
    if (i < N) { row_start[i] = excl; cursor[i] = excl; }
    if (i == N - 1) row_start[N] = E;
}

__global__ __launch_bounds__(256) void csr_scatter(
    const int* __restrict__ ei, int* __restrict__ cursor,
    int2* __restrict__ csr2, int E)
{
    int gid = blockIdx.x * 256 + threadIdx.x;
    if (gid < E) {
        int d = ei[E + gid];
        int pos = atomicAdd(&cursor[d], 1);
        csr2[pos] = make_int2(ei[gid], gid);
    }
}

// ---------------------------------------------------------------------------
// K2: pull gather. wave = dst node (grid-stride), lane = column.
//     2048 blocks = 8192 waves = exactly full wave subscription (32/CU).
// ---------------------------------------------------------------------------
__global__ __launch_bounds__(256) void node_gather(
    const float* __restrict__ ea,
    const int*   __restrict__ row_start, // [N+1]
    const int2*  __restrict__ csr2,      // [E] (src, eid)
    const float* __restrict__ We, const float* __restrict__ be,
    const float* __restrict__ q, const float* __restrict__ k,
    const float* __restrict__ v, const float* __restrict__ xr,
    const float* __restrict__ A, const float* __restrict__ qbe,
    const float* __restrict__ Wbeta,
    float* __restrict__ out, float* __restrict__ S1p, float* __restrict__ S2p,
    int N)
{
    __shared__ float l1[4][D];
    __shared__ float l2[4][D];
    int lane = threadIdx.x & 63;
    int w    = threadIdx.x >> 6;
    int t    = lane & 7;

    float rWe[ED];
    #pragma unroll
    for (int i = 0; i < ED; ++i) rWe[i] = We[i * D + lane];
    float bev = be[lane];
    float wb0 = Wbeta[lane], wb1 = Wbeta[D + lane], wb2 = Wbeta[2 * D + lane];

    float s1bn = 0.f, s2bn = 0.f;
    int stride = gridDim.x * 4;

    for (int nid = blockIdx.x * 4 + w; nid < N; nid += stride) {
        int rs  = row_start[nid];
        int deg = row_start[nid + 1] - rs;

        float  qv   = q[(size_t)nid * D + lane];
        float2 a01  = ((const float2*)A)[(size_t)nid * 64 + lane];
        float  qbeh = qbe[(size_t)nid * 8 + (lane >> 3)];

        float acc = 0.f, den = 0.f, s0 = 0.f, s1 = 0.f;

        int2 se = make_int2(0, 0);
        if (lane < deg) se = csr2[rs + lane];

        int nb = (deg < 64) ? deg : 64;
        for (int j0 = 0; j0 < nb; j0 += 4) {
            int m = nb - j0; if (m > 4) m = 4;
            float kvv[4], vvv[4]; float2 ea2[4];
            #pragma unroll
            for (int j = 0; j < 4; ++j) {
                int jj  = (j < m) ? (j0 + j) : j0;
                int s   = __builtin_amdgcn_readlane(se.x, jj);
                int eid = __builtin_amdgcn_readlane(se.y, jj);
                kvv[j] = k[(size_t)s * D + lane];
                vvv[j] = v[(size_t)s * D + lane];
                ea2[j] = *(const float2*)(ea + (size_t)eid * ED + 2 * t);
            }
            #pragma unroll
            for (int j = 0; j < 4; ++j) {
                if (j < m) {
                    float c = qv * kvv[j] + ea2[j].x * a01.x + ea2[j].y * a01.y;
                    c += __shfl_xor(c, 1);
                    c += __shfl_xor(c, 2);
                    c += __shfl_xor(c, 4);
                    float p = __expf(c + qbeh);
                    acc += p * vvv[j];
                    den += p;
                    s0  += p * ea2[j].x;
                    s1  += p * ea2[j].y;
                }
            }
        }
        // rare fallback: degree > 64
        for (int j = 64; j < deg; ++j) {
            int2 se2 = csr2[rs + j];
            float kvv = k[(size_t)se2.x * D + lane];
            float vvv = v[(size_t)se2.x * D + lane];
            float2 e2 = *(const float2*)(ea + (size_t)se2.y * ED + 2 * t);
            float c = qv * kvv + e2.x * a01.x + e2.y * a01.y;
            c += __shfl_xor(c, 1);
            c += __shfl_xor(c, 2);
            c += __shfl_xor(c, 4);
            float p = __expf(c + qbeh);
            acc += p * vvv; den += p;
            s0 += p * e2.x; s1 += p * e2.y;
        }

        // recombine e-side V: esum_l = sum_i We[i,l]*s[h,i]
        float esum = 0.f;
        #pragma unroll
        for (int i = 0; i < ED; ++i) {
            int srcl = (lane & 56) + (i >> 1);
            float sv = (i & 1) ? __shfl(s1, srcl) : __shfl(s0, srcl);
            esum += sv * rWe[i];
        }

        float o   = (acc + esum + bev * den) / (den + 1e-16f);
        float xrv = xr[(size_t)nid * D + lane];
        float tb  = o * wb0 + xrv * wb1 + (o - xrv) * wb2;
        #pragma unroll
        for (int s = 1; s < 64; s <<= 1) tb += __shfl_xor(tb, s);
        float g  = 1.f / (1.f + __expf(-tb));
        float o2 = g * xrv + (1.f - g) * o;
        out[(size_t)nid * D + lane] = o2;
        s1bn += o2; s2bn += o2 * o2;
    }

    l1[w][lane] = s1bn; l2[w][lane] = s2bn;
    __syncthreads();
    if (threadIdx.x < D) {
        float a = l1[0][threadIdx.x] + l1[1][threadIdx.x]
                + l1[2][threadIdx.x] + l1[3][threadIdx.x];
        float b = l2[0][threadIdx.x] + l2[1][threadIdx.x]
                + l2[2][threadIdx.x] + l2[3][threadIdx.x];
        unsafeAtomicAdd(&S1p[threadIdx.x * 64], a);
        unsafeAtomicAdd(&S2p[threadIdx.x * 64], b);
    }
}

// ---------------------------------------------------------------------------
// K4: batchnorm finalize + apply + LeakyReLU, float4 in place on d_out.
// ---------------------------------------------------------------------------
__global__ __launch_bounds__(256) void bn_apply(
    float4* __restrict__ out, const float* __restrict__ S1p,
    const float* __restrict__ S2p, const float* __restrict__ gamma,
    const float* __restrict__ beta, int total4, float invN)
{
    int gid = blockIdx.x * 256 + threadIdx.x;
    if (gid >= total4) return;
    int col = (gid & 15) * 4;
    float4 g4 = *(const float4*)(gamma + col);
    float4 b4 = *(const float4*)(beta + col);
    float4 y  = out[gid];
    #pragma unroll
    for (int j = 0; j < 4; ++j) {
        float mean = S1p[(col + j) * 64] * invN;
        float var  = S2p[(col + j) * 64] * invN - mean * mean;
        float sc   = (&g4.x)[j] * rsqrtf(var + 1e-5f);
        float sh   = (&b4.x)[j] - mean * sc;
        float tv   = (&y.x)[j] * sc + sh;
        (&y.x)[j]  = (tv >= 0.f) ? tv : 0.01f * tv;
    }
    out[gid] = y;
}

// ---------------------------------------------------------------------------
extern "C" void kernel_launch(void* const* d_in, const int* in_sizes, int n_in,
                              void* d_out, int out_size, void* d_ws, size_t ws_size,
                              hipStream_t stream)
{
    const float* x     = (const float*)d_in[0];
    const int*   ei    = (const int*)  d_in[1];
    const float* ea    = (const float*)d_in[2];
    const float* Wq    = (const float*)d_in[3];
    const float* bq    = (const float*)d_in[4];
    const float* Wk    = (const float*)d_in[5];
    const float* bk    = (const float*)d_in[6];
    const float* Wv    = (const float*)d_in[7];
    const float* bv    = (const float*)d_in[8];
    const float* We    = (const float*)d_in[9];
    const float* be    = (const float*)d_in[10];
    const float* Wskip = (const float*)d_in[11];
    const float* bskip = (const float*)d_in[12];
    const float* Wbeta = (const float*)d_in[13];
    const float* gamma = (const float*)d_in[14];
    const float* betab = (const float*)d_in[15];

    int N = in_sizes[0] / D;   // 50000
    int E = in_sizes[1] / 2;   // 800000

    // ws layout (int units)
    int*   ws        = (int*)d_ws;
    int*   cnt       = ws;                         // 50000 (also scatter cursor)
    float* S1p       = (float*)(ws + 50000);       // 4096 padded col sums
    float* S2p       = (float*)(ws + 54096);       // 4096
    int*   row_start = ws + 58192;                 // 50004
    int*   bsum      = ws + 108196;                // 50000 (scan block sums)
    int2*  csr2      = (int2*)(ws + 158200);       // 2*800000 ints, 8B aligned
    float* q         = (float*)(ws + 1758208);     // 3.2M, 16B aligned
    float* k         = q + 3200000;
    float* v         = k + 3200000;
    float* xr        = v + 3200000;
    float* A         = xr + 3200000;               // 6.4M
    float* qbe       = A + 6400000;                // 400000

    // zero cnt + S1p + S2p (contiguous)
    hipMemsetAsync(d_ws, 0, (size_t)58192 * sizeof(int), stream);

    node_proj<<<(N + 63) / 64, 256, 0, stream>>>(
        x, Wq, bq, Wk, bk, Wv, bv, Wskip, bskip, q, k, v, xr, N);

    aproj<<<(N + 3) / 4, 256, 0, stream>>>(q, We, be, A, qbe, N);

    int nb = (N + 255) / 256;   // 196
    csr_hist<<<(E + 255) / 256, 256, 0, stream>>>(ei, cnt, E);
    scan_a<<<nb, 256, 0, stream>>>(cnt, bsum, N);
    scan_b<<<1, 256, 0, stream>>>(bsum, nb);
    scan_c<<<nb, 256, 0, stream>>>(cnt, bsum, row_start, cnt, N, E);
    csr_scatter<<<(E + 255) / 256, 256, 0, stream>>>(ei, cnt, csr2, E);

    node_gather<<<2048, 256, 0, stream>>>(
        ea, row_start, csr2, We, be, q, k, v, xr, A, qbe, Wbeta,
        (float*)d_out, S1p, S2p, N);

    bn_apply<<<(N * 16 + 255) / 256, 256, 0, stream>>>(
        (float4*)d_out, S1p, S2p, gamma, betab, N * 16, 1.0f / (float)N);
}

// Round 7
// 263.557 us; speedup vs baseline: 1.1216x; 1.1216x over previous
//
#include <hip/hip_runtime.h>

#define D   64
#define H   8
#define DH  8
#define ED  16
#define QK_SCALE 0.35355339059327373f   // 1/sqrt(8)

typedef unsigned int uint_t;

__device__ __forceinline__ void fma4(float4& a, float s, const float4& w) {
    a.x += s * w.x; a.y += s * w.y; a.z += s * w.z; a.w += s * w.w;
}
__device__ __forceinline__ uint_t f2bf(float f) {           // RNE f32->bf16
    uint_t u = __float_as_uint(f);
    return (u + 0x7FFFu + ((u >> 16) & 1u)) >> 16;
}
__device__ __forceinline__ float bf_lo(uint_t u) { return __uint_as_float(u << 16); }
__device__ __forceinline__ float bf_hi(uint_t u) { return __uint_as_float(u & 0xFFFF0000u); }

// ---------------------------------------------------------------------------
// K1 fused: [node_proj blocks | csr_hist blocks]
//   proj: q(f32, pre-scaled), kv(packed bf16 uint), xr(f32)
// ---------------------------------------------------------------------------
__global__ __launch_bounds__(256) void fused_proj_hist(
    const float* __restrict__ x,
    const float* __restrict__ Wq, const float* __restrict__ bq,
    const float* __restrict__ Wk, const float* __restrict__ bk,
    const float* __restrict__ Wv, const float* __restrict__ bv,
    const float* __restrict__ Ws, const float* __restrict__ bs,
    float* __restrict__ q, uint_t* __restrict__ kvp,
    float* __restrict__ xr, int N,
    const int* __restrict__ ei, int* __restrict__ cnt, int E, int projBlocks)
{
    __shared__ float sW[4][D * D];          // 64 KB
    if (blockIdx.x >= projBlocks) {
        int gid = (blockIdx.x - projBlocks) * 256 + threadIdx.x;
        if (gid < E) atomicAdd(&cnt[ei[E + gid]], 1);
        return;
    }
    {
        const float* wsrc[4] = {Wq, Wk, Wv, Ws};
        for (int m = 0; m < 4; ++m)
            for (int t = threadIdx.x; t < D * D; t += 256)
                sW[m][t] = wsrc[m][t];
    }
    __syncthreads();

    int cg = (threadIdx.x & 15) * 4;
    float4 vbq = *(const float4*)(bq + cg);
    float4 vbk = *(const float4*)(bk + cg);
    float4 vbv = *(const float4*)(bv + cg);
    float4 vbs = *(const float4*)(bs + cg);

    #pragma unroll 1
    for (int it = 0; it < 4; ++it) {
        int node = blockIdx.x * 64 + it * 16 + (threadIdx.x >> 4);
        if (node >= N) return;

        float4 aq = {0,0,0,0}, ak = {0,0,0,0}, av = {0,0,0,0}, as_ = {0,0,0,0};
        const float* xrow = x + (size_t)node * D;

        #pragma unroll
        for (int i = 0; i < D; i += 4) {
            float4 xv = *(const float4*)(xrow + i);
            #pragma unroll
            for (int s = 0; s < 4; ++s) {
                float xs = (&xv.x)[s];
                fma4(aq, xs, *(const float4*)(&sW[0][(i + s) * D + cg]));
                fma4(ak, xs, *(const float4*)(&sW[1][(i + s) * D + cg]));
                fma4(av, xs, *(const float4*)(&sW[2][(i + s) * D + cg]));
                fma4(as_, xs, *(const float4*)(&sW[3][(i + s) * D + cg]));
            }
        }
        aq.x = (aq.x + vbq.x) * QK_SCALE;
        aq.y = (aq.y + vbq.y) * QK_SCALE;
        aq.z = (aq.z + vbq.z) * QK_SCALE;
        aq.w = (aq.w + vbq.w) * QK_SCALE;
        ak.x += vbk.x; ak.y += vbk.y; ak.z += vbk.z; ak.w += vbk.w;
        av.x += vbv.x; av.y += vbv.y; av.z += vbv.z; av.w += vbv.w;
        as_.x += vbs.x; as_.y += vbs.y; as_.z += vbs.z; as_.w += vbs.w;

        size_t o = (size_t)node * D + cg;
        *(float4*)(q  + o) = aq;
        *(float4*)(xr + o) = as_;
        uint4 pkv;
        pkv.x = f2bf(ak.x) | (f2bf(av.x) << 16);
        pkv.y = f2bf(ak.y) | (f2bf(av.y) << 16);
        pkv.z = f2bf(ak.z) | (f2bf(av.z) << 16);
        pkv.w = f2bf(ak.w) | (f2bf(av.w) << 16);
        *(uint4*)(kvp + o) = pkv;
    }
}

// ---------------------------------------------------------------------------
// K2 fused: [scan_a blocks | ea bf16-pack blocks]
// ---------------------------------------------------------------------------
__global__ __launch_bounds__(256) void fused_scan_eapack(
    const int* __restrict__ cnt, int* __restrict__ bsum, int N, int scanBlocks,
    const float2* __restrict__ ea2, uint_t* __restrict__ eap, long npairs)
{
    __shared__ int red[256];
    int t = threadIdx.x;
    if (blockIdx.x < scanBlocks) {
        int i = blockIdx.x * 256 + t;
        red[t] = (i < N) ? cnt[i] : 0;
        __syncthreads();
        for (int s = 128; s > 0; s >>= 1) {
            if (t < s) red[t] += red[t + s];
            __syncthreads();
        }
        if (t == 0) bsum[blockIdx.x] = red[0];
        return;
    }
    long i0 = (long)(blockIdx.x - scanBlocks) * 256 + t;
    long stride = (long)(gridDim.x - scanBlocks) * 256;
    for (long i = i0; i < npairs; i += stride) {
        float2 p = ea2[i];
        eap[i] = f2bf(p.x) | (f2bf(p.y) << 16);
    }
}

__global__ __launch_bounds__(256) void scan_b(int* __restrict__ bsum, int nb)
{
    __shared__ int sh[256];
    int t = threadIdx.x;
    int v = (t < nb) ? bsum[t] : 0;
    sh[t] = v;
    __syncthreads();
    for (int s = 1; s < 256; s <<= 1) {
        int a = (t >= s) ? sh[t - s] : 0;
        __syncthreads();
        sh[t] += a;
        __syncthreads();
    }
    if (t < nb) bsum[t] = sh[t] - v;   // exclusive
}

__global__ __launch_bounds__(256) void scan_c(
    const int* __restrict__ cnt, const int* __restrict__ bsum,
    int* __restrict__ row_start, int* __restrict__ cursor, int N, int E)
{
    __shared__ int sh[256];
    int t = threadIdx.x;
    int i = blockIdx.x * 256 + t;
    int v = (i < N) ? cnt[i] : 0;
    sh[t] = v;
    __syncthreads();
    for (int s = 1; s < 256; s <<= 1) {
        int a = (t >= s) ? sh[t - s] : 0;
        __syncthreads();
        sh[t] += a;
        __syncthreads();
    }
    int excl = sh[t] - v + bsum[blockIdx.x];
    if (i < N) { row_start[i] = excl; cursor[i] = excl; }
    if (i == N - 1) row_start[N] = E;
}

// ---------------------------------------------------------------------------
// K5 fused: [csr_scatter blocks | aproj blocks]
//   aproj: A packed bf16 (a0,a1) per lane; qbe f32.
// ---------------------------------------------------------------------------
__global__ __launch_bounds__(256) void fused_scatter_aproj(
    const int* __restrict__ ei, int* __restrict__ cursor,
    int2* __restrict__ csr2, int E, int scatBlocks,
    const float* __restrict__ q, const float* __restrict__ We,
    const float* __restrict__ be, uint_t* __restrict__ Ap,
    float* __restrict__ qbe, int N)
{
    __shared__ float sWe[ED * D];
    __shared__ float sbe[D];
    if (blockIdx.x < scatBlocks) {
        int gid = blockIdx.x * 256 + threadIdx.x;
        if (gid < E) {
            int d = ei[E + gid];
            int pos = atomicAdd(&cursor[d], 1);
            csr2[pos] = make_int2(ei[gid], gid);
        }
        return;
    }
    for (int t = threadIdx.x; t < ED * D; t += 256) sWe[t] = We[t];
    if (threadIdx.x < D) sbe[threadIdx.x] = be[threadIdx.x];
    __syncthreads();

    int lane = threadIdx.x & 63;
    int w    = threadIdx.x >> 6;
    int h = lane >> 3, t = lane & 7;
    int ablocks = gridDim.x - scatBlocks;
    int stride  = ablocks * 4;

    for (int nid = (blockIdx.x - scatBlocks) * 4 + w; nid < N; nid += stride) {
        float qv = q[(size_t)nid * D + lane];
        float a0 = 0.f, a1 = 0.f, qb = 0.f;
        #pragma unroll
        for (int dh = 0; dh < 8; ++dh) {
            float qd = __shfl(qv, (lane & 56) + dh);
            a0 += qd * sWe[(2 * t)     * D + h * 8 + dh];
            a1 += qd * sWe[(2 * t + 1) * D + h * 8 + dh];
            qb += qd * sbe[h * 8 + dh];
        }
        Ap[(size_t)nid * 64 + lane] = f2bf(a0) | (f2bf(a1) << 16);
        if (t == 0) qbe[(size_t)nid * 8 + h] = qb;
    }
}

// ---------------------------------------------------------------------------
// K6: pull gather (bf16 kv/ea/A). wave = dst node, lane = column.
// ---------------------------------------------------------------------------
__global__ __launch_bounds__(256) void node_gather(
    const int*   __restrict__ row_start, // [N+1]
    const int2*  __restrict__ csr2,      // [E] (src, eid)
    const uint_t* __restrict__ eap,      // [E*8] bf16x2
    const float* __restrict__ We, const float* __restrict__ be,
    const float* __restrict__ q, const uint_t* __restrict__ kvp,
    const float* __restrict__ xr,
    const uint_t* __restrict__ Ap, const float* __restrict__ qbe,
    const float* __restrict__ Wbeta,
    float* __restrict__ out, float* __restrict__ S1p, float* __restrict__ S2p,
    int N)
{
    __shared__ float l1[4][D];
    __shared__ float l2[4][D];
    int lane = threadIdx.x & 63;
    int w    = threadIdx.x >> 6;
    int t    = lane & 7;

    float rWe[ED];
    #pragma unroll
    for (int i = 0; i < ED; ++i) rWe[i] = We[i * D + lane];
    float bev = be[lane];
    float wb0 = Wbeta[lane], wb1 = Wbeta[D + lane], wb2 = Wbeta[2 * D + lane];

    float s1bn = 0.f, s2bn = 0.f;
    int stride = gridDim.x * 4;

    for (int nid = blockIdx.x * 4 + w; nid < N; nid += stride) {
        int rs  = row_start[nid];
        int deg = row_start[nid + 1] - rs;

        float  qv   = q[(size_t)nid * D + lane];
        uint_t au   = Ap[(size_t)nid * 64 + lane];
        float  a0   = bf_lo(au), a1 = bf_hi(au);
        float  qbeh = qbe[(size_t)nid * 8 + (lane >> 3)];

        float acc = 0.f, den = 0.f, s0 = 0.f, s1 = 0.f;

        int2 se = make_int2(0, 0);
        if (lane < deg) se = csr2[rs + lane];

        int nb = (deg < 64) ? deg : 64;
        for (int j0 = 0; j0 < nb; j0 += 4) {
            int m = nb - j0; if (m > 4) m = 4;
            uint_t kvu[4], eau[4];
            #pragma unroll
            for (int j = 0; j < 4; ++j) {
                int jj  = (j < m) ? (j0 + j) : j0;
                int s   = __builtin_amdgcn_readlane(se.x, jj);
                int eid = __builtin_amdgcn_readlane(se.y, jj);
                kvu[j] = kvp[(size_t)s * D + lane];
                eau[j] = eap[(size_t)eid * 8 + t];
            }
            #pragma unroll
            for (int j = 0; j < 4; ++j) {
                if (j < m) {
                    float kf = bf_lo(kvu[j]), vf = bf_hi(kvu[j]);
                    float ex = bf_lo(eau[j]), ey = bf_hi(eau[j]);
                    float c = qv * kf + ex * a0 + ey * a1;
                    c += __shfl_xor(c, 1);
                    c += __shfl_xor(c, 2);
                    c += __shfl_xor(c, 4);
                    float p = __expf(c + qbeh);
                    acc += p * vf;
                    den += p;
                    s0  += p * ex;
                    s1  += p * ey;
                }
            }
        }
        // rare fallback: degree > 64
        for (int j = 64; j < deg; ++j) {
            int2 se2 = csr2[rs + j];
            uint_t kvu = kvp[(size_t)se2.x * D + lane];
            uint_t eau = eap[(size_t)se2.y * 8 + t];
            float kf = bf_lo(kvu), vf = bf_hi(kvu);
            float ex = bf_lo(eau), ey = bf_hi(eau);
            float c = qv * kf + ex * a0 + ey * a1;
            c += __shfl_xor(c, 1);
            c += __shfl_xor(c, 2);
            c += __shfl_xor(c, 4);
            float p = __expf(c + qbeh);
            acc += p * vf; den += p;
            s0 += p * ex; s1 += p * ey;
        }

        // recombine e-side V: esum_l = sum_i We[i,l]*s[h,i]
        float esum = 0.f;
        #pragma unroll
        for (int i = 0; i < ED; ++i) {
            int srcl = (lane & 56) + (i >> 1);
            float sv = (i & 1) ? __shfl(s1, srcl) : __shfl(s0, srcl);
            esum += sv * rWe[i];
        }

        float o   = (acc + esum + bev * den) / (den + 1e-16f);
        float xrv = xr[(size_t)nid * D + lane];
        float tb  = o * wb0 + xrv * wb1 + (o - xrv) * wb2;
        #pragma unroll
        for (int s = 1; s < 64; s <<= 1) tb += __shfl_xor(tb, s);
        float g  = 1.f / (1.f + __expf(-tb));
        float o2 = g * xrv + (1.f - g) * o;
        out[(size_t)nid * D + lane] = o2;
        s1bn += o2; s2bn += o2 * o2;
    }

    l1[w][lane] = s1bn; l2[w][lane] = s2bn;
    __syncthreads();
    if (threadIdx.x < D) {
        float a = l1[0][threadIdx.x] + l1[1][threadIdx.x]
                + l1[2][threadIdx.x] + l1[3][threadIdx.x];
        float b = l2[0][threadIdx.x] + l2[1][threadIdx.x]
                + l2[2][threadIdx.x] + l2[3][threadIdx.x];
        unsafeAtomicAdd(&S1p[threadIdx.x * 64], a);
        unsafeAtomicAdd(&S2p[threadIdx.x * 64], b);
    }
}

// ---------------------------------------------------------------------------
// K7: batchnorm finalize + apply + LeakyReLU, float4 in place on d_out.
// ---------------------------------------------------------------------------
__global__ __launch_bounds__(256) void bn_apply(
    float4* __restrict__ out, const float* __restrict__ S1p,
    const float* __restrict__ S2p, const float* __restrict__ gamma,
    const float* __restrict__ beta, int total4, float invN)
{
    int gid = blockIdx.x * 256 + threadIdx.x;
    if (gid >= total4) return;
    int col = (gid & 15) * 4;
    float4 g4 = *(const float4*)(gamma + col);
    float4 b4 = *(const float4*)(beta + col);
    float4 y  = out[gid];
    #pragma unroll
    for (int j = 0; j < 4; ++j) {
        float mean = S1p[(col + j) * 64] * invN;
        float var  = S2p[(col + j) * 64] * invN - mean * mean;
        float sc   = (&g4.x)[j] * rsqrtf(var + 1e-5f);
        float sh   = (&b4.x)[j] - mean * sc;
        float tv   = (&y.x)[j] * sc + sh;
        (&y.x)[j]  = (tv >= 0.f) ? tv : 0.01f * tv;
    }
    out[gid] = y;
}

// ---------------------------------------------------------------------------
extern "C" void kernel_launch(void* const* d_in, const int* in_sizes, int n_in,
                              void* d_out, int out_size, void* d_ws, size_t ws_size,
                              hipStream_t stream)
{
    const float* x     = (const float*)d_in[0];
    const int*   ei    = (const int*)  d_in[1];
    const float* ea    = (const float*)d_in[2];
    const float* Wq    = (const float*)d_in[3];
    const float* bq    = (const float*)d_in[4];
    const float* Wk    = (const float*)d_in[5];
    const float* bk    = (const float*)d_in[6];
    const float* Wv    = (const float*)d_in[7];
    const float* bv    = (const float*)d_in[8];
    const float* We    = (const float*)d_in[9];
    const float* be    = (const float*)d_in[10];
    const float* Wskip = (const float*)d_in[11];
    const float* bskip = (const float*)d_in[12];
    const float* Wbeta = (const float*)d_in[13];
    const float* gamma = (const float*)d_in[14];
    const float* betab = (const float*)d_in[15];

    int N = in_sizes[0] / D;   // 50000
    int E = in_sizes[1] / 2;   // 800000

    // ws layout (int units)
    int*    ws        = (int*)d_ws;
    int*    cnt       = ws;                         // 50000 (also scatter cursor)
    float*  S1p       = (float*)(ws + 50000);       // 4096 padded col sums
    float*  S2p       = (float*)(ws + 54096);       // 4096
    int*    row_start = ws + 58192;                 // 50004
    int*    bsum      = ws + 108196;                // 604 pad
    int2*   csr2      = (int2*)(ws + 108800);       // 1.6M ints, 8B aligned
    uint_t* kvp       = (uint_t*)(ws + 1708800);    // 3.2M
    float*  q         = (float*)(ws + 4908800);     // 3.2M
    float*  xr        = (float*)(ws + 8108800);     // 3.2M
    uint_t* Ap        = (uint_t*)(ws + 11308800);   // 3.2M
    uint_t* eap       = (uint_t*)(ws + 14508800);   // 6.4M
    float*  qbe       = (float*)(ws + 20908800);    // 400000

    // zero cnt + S1p + S2p (contiguous)
    hipMemsetAsync(d_ws, 0, (size_t)58192 * sizeof(int), stream);

    int projB = (N + 63) / 64;      // 782
    int histB = (E + 255) / 256;    // 3125
    fused_proj_hist<<<projB + histB, 256, 0, stream>>>(
        x, Wq, bq, Wk, bk, Wv, bv, Wskip, bskip,
        q, kvp, xr, N, ei, cnt, E, projB);

    int scanB = (N + 255) / 256;    // 196
    fused_scan_eapack<<<scanB + 2048, 256, 0, stream>>>(
        cnt, bsum, N, scanB, (const float2*)ea, eap, (long)E * 8);

    scan_b<<<1, 256, 0, stream>>>(bsum, scanB);
    scan_c<<<scanB, 256, 0, stream>>>(cnt, bsum, row_start, cnt, N, E);

    int scatB = (E + 255) / 256;    // 3125
    fused_scatter_aproj<<<scatB + 1024, 256, 0, stream>>>(
        ei, cnt, csr2, E, scatB, q, We, be, Ap, qbe, N);

    node_gather<<<1024, 256, 0, stream>>>(
        row_start, csr2, eap, We, be, q, kvp, xr, Ap, qbe, Wbeta,
        (float*)d_out, S1p, S2p, N);

    bn_apply<<<(N * 16 + 255) / 256, 256, 0, stream>>>(
        (float4*)d_out, S1p, S2p, gamma, betab, N * 16, 1.0f / (float)N);
}

// Round 8
// 248.644 us; speedup vs baseline: 1.1889x; 1.0600x over previous
//
#include <hip/hip_runtime.h>

#define D   64
#define H   8
#define DH  8
#define ED  16
#define QK_SCALE 0.35355339059327373f   // 1/sqrt(8)

typedef unsigned int uint_t;

__device__ __forceinline__ void fma4(float4& a, float s, const float4& w) {
    a.x += s * w.x; a.y += s * w.y; a.z += s * w.z; a.w += s * w.w;
}
__device__ __forceinline__ uint_t f2bf(float f) {           // RNE f32->bf16
    uint_t u = __float_as_uint(f);
    return (u + 0x7FFFu + ((u >> 16) & 1u)) >> 16;
}
__device__ __forceinline__ float bf_lo(uint_t u) { return __uint_as_float(u << 16); }
__device__ __forceinline__ float bf_hi(uint_t u) { return __uint_as_float(u & 0xFFFF0000u); }

// ---------------------------------------------------------------------------
// K1 fused: [node_proj+Aproj blocks | csr_hist blocks]
//   proj: q(f32, pre-scaled), kv(packed bf16), xr(f32),
//         A[n,h,i] (bf16 pairs) and qbe[n,h] computed in-register from q.
// ---------------------------------------------------------------------------
__global__ __launch_bounds__(256) void fused_proj_hist(
    const float* __restrict__ x,
    const float* __restrict__ Wq, const float* __restrict__ bq,
    const float* __restrict__ Wk, const float* __restrict__ bk,
    const float* __restrict__ Wv, const float* __restrict__ bv,
    const float* __restrict__ Ws, const float* __restrict__ bs,
    const float* __restrict__ We, const float* __restrict__ be,
    float* __restrict__ q, uint_t* __restrict__ kvp,
    float* __restrict__ xr, uint_t* __restrict__ Ap, float* __restrict__ qbe,
    int N,
    const int* __restrict__ ei, int* __restrict__ cnt, int E, int projBlocks)
{
    __shared__ float sW[4][D * D];          // 64 KB
    __shared__ float sWe[ED * D];           // 4 KB
    __shared__ float sbe[D];
    if (blockIdx.x >= projBlocks) {
        int gid = (blockIdx.x - projBlocks) * 256 + threadIdx.x;
        if (gid < E) atomicAdd(&cnt[ei[E + gid]], 1);
        return;
    }
    {
        const float* wsrc[4] = {Wq, Wk, Wv, Ws};
        for (int m = 0; m < 4; ++m)
            for (int t = threadIdx.x; t < D * D; t += 256)
                sW[m][t] = wsrc[m][t];
        for (int t = threadIdx.x; t < ED * D; t += 256) sWe[t] = We[t];
        if (threadIdx.x < D) sbe[threadIdx.x] = be[threadIdx.x];
    }
    __syncthreads();

    int cg = (threadIdx.x & 15) * 4;
    float4 vbq = *(const float4*)(bq + cg);
    float4 vbk = *(const float4*)(bk + cg);
    float4 vbv = *(const float4*)(bv + cg);
    float4 vbs = *(const float4*)(bs + cg);
    int h  = cg >> 3;
    int hh = (cg >> 2) & 1;

    #pragma unroll 1
    for (int it = 0; it < 4; ++it) {
        int node = blockIdx.x * 64 + it * 16 + (threadIdx.x >> 4);
        if (node >= N) return;

        float4 aq = {0,0,0,0}, ak = {0,0,0,0}, av = {0,0,0,0}, as_ = {0,0,0,0};
        const float* xrow = x + (size_t)node * D;

        #pragma unroll
        for (int i = 0; i < D; i += 4) {
            float4 xv = *(const float4*)(xrow + i);
            #pragma unroll
            for (int s = 0; s < 4; ++s) {
                float xs = (&xv.x)[s];
                fma4(aq, xs, *(const float4*)(&sW[0][(i + s) * D + cg]));
                fma4(ak, xs, *(const float4*)(&sW[1][(i + s) * D + cg]));
                fma4(av, xs, *(const float4*)(&sW[2][(i + s) * D + cg]));
                fma4(as_, xs, *(const float4*)(&sW[3][(i + s) * D + cg]));
            }
        }
        aq.x = (aq.x + vbq.x) * QK_SCALE;
        aq.y = (aq.y + vbq.y) * QK_SCALE;
        aq.z = (aq.z + vbq.z) * QK_SCALE;
        aq.w = (aq.w + vbq.w) * QK_SCALE;
        ak.x += vbk.x; ak.y += vbk.y; ak.z += vbk.z; ak.w += vbk.w;
        av.x += vbv.x; av.y += vbv.y; av.z += vbv.z; av.w += vbv.w;
        as_.x += vbs.x; as_.y += vbs.y; as_.z += vbs.z; as_.w += vbs.w;

        size_t o = (size_t)node * D + cg;
        *(float4*)(q  + o) = aq;
        *(float4*)(xr + o) = as_;
        uint4 pkv;
        pkv.x = f2bf(ak.x) | (f2bf(av.x) << 16);
        pkv.y = f2bf(ak.y) | (f2bf(av.y) << 16);
        pkv.z = f2bf(ak.z) | (f2bf(av.z) << 16);
        pkv.w = f2bf(ak.w) | (f2bf(av.w) << 16);
        *(uint4*)(kvp + o) = pkv;

        // --- merged A projection: A[h,i] = sum_dh q[8h+dh]*We[i,8h+dh] ---
        float part[ED];
        #pragma unroll
        for (int i = 0; i < ED; ++i) {
            float pi = 0.f;
            #pragma unroll
            for (int s = 0; s < 4; ++s)
                pi += (&aq.x)[s] * sWe[i * D + cg + s];
            part[i] = pi;
        }
        float qb = 0.f;
        #pragma unroll
        for (int s = 0; s < 4; ++s) qb += (&aq.x)[s] * sbe[cg + s];
        #pragma unroll
        for (int i = 0; i < ED; ++i) part[i] += __shfl_xor(part[i], 1);
        qb += __shfl_xor(qb, 1);

        uint4 apk;
        apk.x = f2bf(part[hh * 8 + 0]) | (f2bf(part[hh * 8 + 1]) << 16);
        apk.y = f2bf(part[hh * 8 + 2]) | (f2bf(part[hh * 8 + 3]) << 16);
        apk.z = f2bf(part[hh * 8 + 4]) | (f2bf(part[hh * 8 + 5]) << 16);
        apk.w = f2bf(part[hh * 8 + 6]) | (f2bf(part[hh * 8 + 7]) << 16);
        *(uint4*)(Ap + (size_t)node * 64 + h * 8 + hh * 4) = apk;
        if (hh == 0) qbe[(size_t)node * 8 + h] = qb;
    }
}

// ---------------------------------------------------------------------------
// CSR scan (3 stages)
// ---------------------------------------------------------------------------
__global__ __launch_bounds__(256) void scan_a(
    const int* __restrict__ cnt, int* __restrict__ bsum, int N)
{
    __shared__ int red[256];
    int t = threadIdx.x;
    int i = blockIdx.x * 256 + t;
    red[t] = (i < N) ? cnt[i] : 0;
    __syncthreads();
    for (int s = 128; s > 0; s >>= 1) {
        if (t < s) red[t] += red[t + s];
        __syncthreads();
    }
    if (t == 0) bsum[blockIdx.x] = red[0];
}

__global__ __launch_bounds__(256) void scan_b(int* __restrict__ bsum, int nb)
{
    __shared__ int sh[256];
    int t = threadIdx.x;
    int v = (t < nb) ? bsum[t] : 0;
    sh[t] = v;
    __syncthreads();
    for (int s = 1; s < 256; s <<= 1) {
        int a = (t >= s) ? sh[t - s] : 0;
        __syncthreads();
        sh[t] += a;
        __syncthreads();
    }
    if (t < nb) bsum[t] = sh[t] - v;   // exclusive
}

__global__ __launch_bounds__(256) void scan_c(
    const int* __restrict__ cnt, const int* __restrict__ bsum,
    int* __restrict__ row_start, int* __restrict__ cursor, int N, int E)
{
    __shared__ int sh[256];
    int t = threadIdx.x;
    int i = blockIdx.x * 256 + t;
    int v = (i < N) ? cnt[i] : 0;
    sh[t] = v;
    __syncthreads();
    for (int s = 1; s < 256; s <<= 1) {
        int a = (t >= s) ? sh[t - s] : 0;
        __syncthreads();
        sh[t] += a;
        __syncthreads();
    }
    int excl = sh[t] - v + bsum[blockIdx.x];
    if (i < N) { row_start[i] = excl; cursor[i] = excl; }
    if (i == N - 1) row_start[N] = E;
}

// ---------------------------------------------------------------------------
// K5: payload scatter. Writes srcs_s[pos] and ea_s[pos] (bf16-packed row)
//     in CSR order so the gather reads pure sequential streams.
// ---------------------------------------------------------------------------
__global__ __launch_bounds__(256) void csr_scatter(
    const int* __restrict__ ei, const float4* __restrict__ ea4,
    int* __restrict__ cursor, int* __restrict__ srcs_s,
    uint_t* __restrict__ ea_s, int E)
{
    int gid = blockIdx.x * 256 + threadIdx.x;
    if (gid >= E) return;
    int src = ei[gid];
    int dst = ei[E + gid];
    float4 r0 = ea4[(size_t)gid * 4 + 0];
    float4 r1 = ea4[(size_t)gid * 4 + 1];
    float4 r2 = ea4[(size_t)gid * 4 + 2];
    float4 r3 = ea4[(size_t)gid * 4 + 3];
    int pos = atomicAdd(&cursor[dst], 1);
    srcs_s[pos] = src;
    uint4 p0, p1;
    p0.x = f2bf(r0.x) | (f2bf(r0.y) << 16);
    p0.y = f2bf(r0.z) | (f2bf(r0.w) << 16);
    p0.z = f2bf(r1.x) | (f2bf(r1.y) << 16);
    p0.w = f2bf(r1.z) | (f2bf(r1.w) << 16);
    p1.x = f2bf(r2.x) | (f2bf(r2.y) << 16);
    p1.y = f2bf(r2.z) | (f2bf(r2.w) << 16);
    p1.z = f2bf(r3.x) | (f2bf(r3.y) << 16);
    p1.w = f2bf(r3.z) | (f2bf(r3.w) << 16);
    *(uint4*)(ea_s + (size_t)pos * 8)     = p0;
    *(uint4*)(ea_s + (size_t)pos * 8 + 4) = p1;
}

// ---------------------------------------------------------------------------
// K6: pull gather. wave = dst node, lane = column. srcs/ea sequential;
//     only kvp is a random gather (12.8MB, L3-resident).
// ---------------------------------------------------------------------------
__global__ __launch_bounds__(256) void node_gather(
    const int*   __restrict__ row_start, // [N+1]
    const int*   __restrict__ srcs_s,    // [E] CSR-ordered src
    const uint_t* __restrict__ ea_s,     // [E*8] CSR-ordered bf16x2
    const float* __restrict__ We, const float* __restrict__ be,
    const float* __restrict__ q, const uint_t* __restrict__ kvp,
    const float* __restrict__ xr,
    const uint_t* __restrict__ Ap, const float* __restrict__ qbe,
    const float* __restrict__ Wbeta,
    float* __restrict__ out, float* __restrict__ S1p, float* __restrict__ S2p,
    int N)
{
    __shared__ float l1[4][D];
    __shared__ float l2[4][D];
    int lane = threadIdx.x & 63;
    int w    = threadIdx.x >> 6;
    int t    = lane & 7;

    float rWe[ED];
    #pragma unroll
    for (int i = 0; i < ED; ++i) rWe[i] = We[i * D + lane];
    float bev = be[lane];
    float wb0 = Wbeta[lane], wb1 = Wbeta[D + lane], wb2 = Wbeta[2 * D + lane];

    float s1bn = 0.f, s2bn = 0.f;
    int stride = gridDim.x * 4;

    for (int nid = blockIdx.x * 4 + w; nid < N; nid += stride) {
        int rs  = row_start[nid];
        int deg = row_start[nid + 1] - rs;

        float  qv   = q[(size_t)nid * D + lane];
        uint_t au   = Ap[(size_t)nid * 64 + lane];
        float  a0   = bf_lo(au), a1 = bf_hi(au);
        float  qbeh = qbe[(size_t)nid * 8 + (lane >> 3)];

        float acc = 0.f, den = 0.f, s0 = 0.f, s1 = 0.f;

        int srcv = 0;
        if (lane < deg) srcv = srcs_s[rs + lane];

        int nb = (deg < 64) ? deg : 64;
        for (int j0 = 0; j0 < nb; j0 += 4) {
            int m = nb - j0; if (m > 4) m = 4;
            // one coalesced load covers the 4 edges' packed ea (32 uints)
            uint_t eald = ea_s[(size_t)(rs + j0) * 8 + (lane & 31)];
            uint_t kvu[4];
            #pragma unroll
            for (int j = 0; j < 4; ++j) {
                int jj = (j < m) ? (j0 + j) : j0;
                int s  = __builtin_amdgcn_readlane(srcv, jj);
                kvu[j] = kvp[(size_t)s * D + lane];
            }
            #pragma unroll
            for (int j = 0; j < 4; ++j) {
                if (j < m) {
                    uint_t eau = __shfl(eald, j * 8 + t);
                    float kf = bf_lo(kvu[j]), vf = bf_hi(kvu[j]);
                    float ex = bf_lo(eau), ey = bf_hi(eau);
                    float c = qv * kf + ex * a0 + ey * a1;
                    c += __shfl_xor(c, 1);
                    c += __shfl_xor(c, 2);
                    c += __shfl_xor(c, 4);
                    float p = __expf(c + qbeh);
                    acc += p * vf;
                    den += p;
                    s0  += p * ex;
                    s1  += p * ey;
                }
            }
        }
        // rare fallback: degree > 64
        for (int j = 64; j < deg; ++j) {
            int s = srcs_s[rs + j];
            uint_t kvu = kvp[(size_t)s * D + lane];
            uint_t eau = ea_s[(size_t)(rs + j) * 8 + t];
            float kf = bf_lo(kvu), vf = bf_hi(kvu);
            float ex = bf_lo(eau), ey = bf_hi(eau);
            float c = qv * kf + ex * a0 + ey * a1;
            c += __shfl_xor(c, 1);
            c += __shfl_xor(c, 2);
            c += __shfl_xor(c, 4);
            float p = __expf(c + qbeh);
            acc += p * vf; den += p;
            s0 += p * ex; s1 += p * ey;
        }

        // recombine e-side V: esum_l = sum_i We[i,l]*s[h,i]
        float esum = 0.f;
        #pragma unroll
        for (int i = 0; i < ED; ++i) {
            int srcl = (lane & 56) + (i >> 1);
            float sv = (i & 1) ? __shfl(s1, srcl) : __shfl(s0, srcl);
            esum += sv * rWe[i];
        }

        float o   = (acc + esum + bev * den) / (den + 1e-16f);
        float xrv = xr[(size_t)nid * D + lane];
        float tb  = o * wb0 + xrv * wb1 + (o - xrv) * wb2;
        #pragma unroll
        for (int s = 1; s < 64; s <<= 1) tb += __shfl_xor(tb, s);
        float g  = 1.f / (1.f + __expf(-tb));
        float o2 = g * xrv + (1.f - g) * o;
        out[(size_t)nid * D + lane] = o2;
        s1bn += o2; s2bn += o2 * o2;
    }

    l1[w][lane] = s1bn; l2[w][lane] = s2bn;
    __syncthreads();
    if (threadIdx.x < D) {
        float a = l1[0][threadIdx.x] + l1[1][threadIdx.x]
                + l1[2][threadIdx.x] + l1[3][threadIdx.x];
        float b = l2[0][threadIdx.x] + l2[1][threadIdx.x]
                + l2[2][threadIdx.x] + l2[3][threadIdx.x];
        unsafeAtomicAdd(&S1p[threadIdx.x * 64], a);
        unsafeAtomicAdd(&S2p[threadIdx.x * 64], b);
    }
}

// ---------------------------------------------------------------------------
// K7: batchnorm finalize + apply + LeakyReLU, float4 in place on d_out.
// ---------------------------------------------------------------------------
__global__ __launch_bounds__(256) void bn_apply(
    float4* __restrict__ out, const float* __restrict__ S1p,
    const float* __restrict__ S2p, const float* __restrict__ gamma,
    const float* __restrict__ beta, int total4, float invN)
{
    int gid = blockIdx.x * 256 + threadIdx.x;
    if (gid >= total4) return;
    int col = (gid & 15) * 4;
    float4 g4 = *(const float4*)(gamma + col);
    float4 b4 = *(const float4*)(beta + col);
    float4 y  = out[gid];
    #pragma unroll
    for (int j = 0; j < 4; ++j) {
        float mean = S1p[(col + j) * 64] * invN;
        float var  = S2p[(col + j) * 64] * invN - mean * mean;
        float sc   = (&g4.x)[j] * rsqrtf(var + 1e-5f);
        float sh   = (&b4.x)[j] - mean * sc;
        float tv   = (&y.x)[j] * sc + sh;
        (&y.x)[j]  = (tv >= 0.f) ? tv : 0.01f * tv;
    }
    out[gid] = y;
}

// ---------------------------------------------------------------------------
extern "C" void kernel_launch(void* const* d_in, const int* in_sizes, int n_in,
                              void* d_out, int out_size, void* d_ws, size_t ws_size,
                              hipStream_t stream)
{
    const float* x     = (const float*)d_in[0];
    const int*   ei    = (const int*)  d_in[1];
    const float* ea    = (const float*)d_in[2];
    const float* Wq    = (const float*)d_in[3];
    const float* bq    = (const float*)d_in[4];
    const float* Wk    = (const float*)d_in[5];
    const float* bk    = (const float*)d_in[6];
    const float* Wv    = (const float*)d_in[7];
    const float* bv    = (const float*)d_in[8];
    const float* We    = (const float*)d_in[9];
    const float* be    = (const float*)d_in[10];
    const float* Wskip = (const float*)d_in[11];
    const float* bskip = (const float*)d_in[12];
    const float* Wbeta = (const float*)d_in[13];
    const float* gamma = (const float*)d_in[14];
    const float* betab = (const float*)d_in[15];

    int N = in_sizes[0] / D;   // 50000
    int E = in_sizes[1] / 2;   // 800000

    // ws layout (uint units); total 20508544 uints = 82.0 MB
    int*    ws        = (int*)d_ws;
    int*    cnt       = ws;                         // 50000 (also scatter cursor)
    float*  S1p       = (float*)(ws + 50000);       // 4096 padded col sums
    float*  S2p       = (float*)(ws + 54096);       // 4096
    int*    row_start = ws + 58192;                 // 50004
    int*    bsum      = ws + 108240;                // 256 (16B aligned)
    int*    srcs_s    = ws + 108544;                // 800000
    uint_t* ea_s      = (uint_t*)(ws + 908544);     // 6400000
    uint_t* kvp       = (uint_t*)(ws + 7308544);    // 3200000
    float*  q         = (float*)(ws + 10508544);    // 3200000
    float*  xr        = (float*)(ws + 13708544);    // 3200000
    uint_t* Ap        = (uint_t*)(ws + 16908544);   // 3200000
    float*  qbe       = (float*)(ws + 20108544);    // 400000

    // zero cnt + S1p + S2p (contiguous)
    hipMemsetAsync(d_ws, 0, (size_t)58192 * sizeof(int), stream);

    int projB = (N + 63) / 64;      // 782
    int histB = (E + 255) / 256;    // 3125
    fused_proj_hist<<<projB + histB, 256, 0, stream>>>(
        x, Wq, bq, Wk, bk, Wv, bv, Wskip, bskip, We, be,
        q, kvp, xr, Ap, qbe, N, ei, cnt, E, projB);

    int scanB = (N + 255) / 256;    // 196
    scan_a<<<scanB, 256, 0, stream>>>(cnt, bsum, N);
    scan_b<<<1, 256, 0, stream>>>(bsum, scanB);
    scan_c<<<scanB, 256, 0, stream>>>(cnt, bsum, row_start, cnt, N, E);

    csr_scatter<<<(E + 255) / 256, 256, 0, stream>>>(
        ei, (const float4*)ea, cnt, srcs_s, ea_s, E);

    node_gather<<<1024, 256, 0, stream>>>(
        row_start, srcs_s, ea_s, We, be, q, kvp, xr, Ap, qbe, Wbeta,
        (float*)d_out, S1p, S2p, N);

    bn_apply<<<(N * 16 + 255) / 256, 256, 0, stream>>>(
        (float4*)d_out, S1p, S2p, gamma, betab, N * 16, 1.0f / (float)N);
}

// Round 9
// 226.318 us; speedup vs baseline: 1.3062x; 1.0987x over previous
//
#include <hip/hip_runtime.h>

#define D   64
#define H   8
#define DH  8
#define ED  16
#define QK_SCALE 0.35355339059327373f   // 1/sqrt(8)

typedef unsigned int uint_t;

__device__ __forceinline__ void fma4(float4& a, float s, const float4& w) {
    a.x += s * w.x; a.y += s * w.y; a.z += s * w.z; a.w += s * w.w;
}
__device__ __forceinline__ uint_t f2bf(float f) {           // RNE f32->bf16
    uint_t u = __float_as_uint(f);
    return (u + 0x7FFFu + ((u >> 16) & 1u)) >> 16;
}
__device__ __forceinline__ float bf_lo(uint_t u) { return __uint_as_float(u << 16); }
__device__ __forceinline__ float bf_hi(uint_t u) { return __uint_as_float(u & 0xFFFF0000u); }

// ---------------------------------------------------------------------------
// K1 fused: [proj_qs blocks | csr_hist blocks]
//   proj_qs: q (f32, pre-scaled by 1/sqrt8), xr (f32), A (bf16 pairs), qbe.
//   LDS = Wq+Ws (32KB) + We (4KB) + be -> ~36.3KB -> 4 blocks/CU.
// ---------------------------------------------------------------------------
__global__ __launch_bounds__(256) void proj_qs_hist(
    const float* __restrict__ x,
    const float* __restrict__ Wq, const float* __restrict__ bq,
    const float* __restrict__ Ws, const float* __restrict__ bs,
    const float* __restrict__ We, const float* __restrict__ be,
    float* __restrict__ q, float* __restrict__ xr,
    uint_t* __restrict__ Ap, float* __restrict__ qbe, int N,
    const int* __restrict__ ei, int* __restrict__ cnt, int E, int projBlocks)
{
    __shared__ float sW[2][D * D];          // 32 KB
    __shared__ float sWe[ED * D];           // 4 KB
    __shared__ float sbe[D];
    if (blockIdx.x >= projBlocks) {
        int gid = (blockIdx.x - projBlocks) * 256 + threadIdx.x;
        if (gid < E) atomicAdd(&cnt[ei[E + gid]], 1);
        return;
    }
    {
        for (int t = threadIdx.x; t < D * D; t += 256) {
            sW[0][t] = Wq[t];
            sW[1][t] = Ws[t];
        }
        for (int t = threadIdx.x; t < ED * D; t += 256) sWe[t] = We[t];
        if (threadIdx.x < D) sbe[threadIdx.x] = be[threadIdx.x];
    }
    __syncthreads();

    int cg = (threadIdx.x & 15) * 4;
    float4 vbq = *(const float4*)(bq + cg);
    float4 vbs = *(const float4*)(bs + cg);
    int h  = cg >> 3;
    int hh = (cg >> 2) & 1;

    #pragma unroll 1
    for (int it = 0; it < 4; ++it) {
        int node = blockIdx.x * 64 + it * 16 + (threadIdx.x >> 4);
        if (node >= N) return;

        float4 aq = {0,0,0,0}, as_ = {0,0,0,0};
        const float* xrow = x + (size_t)node * D;

        #pragma unroll
        for (int i = 0; i < D; i += 4) {
            float4 xv = *(const float4*)(xrow + i);
            #pragma unroll
            for (int s = 0; s < 4; ++s) {
                float xs = (&xv.x)[s];
                fma4(aq,  xs, *(const float4*)(&sW[0][(i + s) * D + cg]));
                fma4(as_, xs, *(const float4*)(&sW[1][(i + s) * D + cg]));
            }
        }
        aq.x = (aq.x + vbq.x) * QK_SCALE;
        aq.y = (aq.y + vbq.y) * QK_SCALE;
        aq.z = (aq.z + vbq.z) * QK_SCALE;
        aq.w = (aq.w + vbq.w) * QK_SCALE;
        as_.x += vbs.x; as_.y += vbs.y; as_.z += vbs.z; as_.w += vbs.w;

        size_t o = (size_t)node * D + cg;
        *(float4*)(q  + o) = aq;
        *(float4*)(xr + o) = as_;

        // --- A projection: A[h,i] = sum_dh q[8h+dh]*We[i,8h+dh] ---
        float part[ED];
        #pragma unroll
        for (int i = 0; i < ED; ++i) {
            float pi = 0.f;
            #pragma unroll
            for (int s = 0; s < 4; ++s)
                pi += (&aq.x)[s] * sWe[i * D + cg + s];
            part[i] = pi;
        }
        float qb = 0.f;
        #pragma unroll
        for (int s = 0; s < 4; ++s) qb += (&aq.x)[s] * sbe[cg + s];
        #pragma unroll
        for (int i = 0; i < ED; ++i) part[i] += __shfl_xor(part[i], 1);
        qb += __shfl_xor(qb, 1);

        uint4 apk;
        apk.x = f2bf(part[hh * 8 + 0]) | (f2bf(part[hh * 8 + 1]) << 16);
        apk.y = f2bf(part[hh * 8 + 2]) | (f2bf(part[hh * 8 + 3]) << 16);
        apk.z = f2bf(part[hh * 8 + 4]) | (f2bf(part[hh * 8 + 5]) << 16);
        apk.w = f2bf(part[hh * 8 + 6]) | (f2bf(part[hh * 8 + 7]) << 16);
        *(uint4*)(Ap + (size_t)node * 64 + h * 8 + hh * 4) = apk;
        if (hh == 0) qbe[(size_t)node * 8 + h] = qb;
    }
}

// ---------------------------------------------------------------------------
// K2 fused: [proj_kv blocks | scan_a blocks]
//   proj_kv: kvp packed bf16 (k lo, v hi). LDS = Wk+Wv (32KB) -> 4-5 blocks/CU.
// ---------------------------------------------------------------------------
__global__ __launch_bounds__(256) void proj_kv_scana(
    const float* __restrict__ x,
    const float* __restrict__ Wk, const float* __restrict__ bk,
    const float* __restrict__ Wv, const float* __restrict__ bv,
    uint_t* __restrict__ kvp, int N, int kvBlocks,
    const int* __restrict__ cnt, int* __restrict__ bsum)
{
    __shared__ float sW[2][D * D];          // 32 KB
    __shared__ int red[256];
    if (blockIdx.x >= kvBlocks) {
        int t = threadIdx.x;
        int i = (blockIdx.x - kvBlocks) * 256 + t;
        red[t] = (i < N) ? cnt[i] : 0;
        __syncthreads();
        for (int s = 128; s > 0; s >>= 1) {
            if (t < s) red[t] += red[t + s];
            __syncthreads();
        }
        if (t == 0) bsum[blockIdx.x - kvBlocks] = red[0];
        return;
    }
    for (int t = threadIdx.x; t < D * D; t += 256) {
        sW[0][t] = Wk[t];
        sW[1][t] = Wv[t];
    }
    __syncthreads();

    int cg = (threadIdx.x & 15) * 4;
    float4 vbk = *(const float4*)(bk + cg);
    float4 vbv = *(const float4*)(bv + cg);

    #pragma unroll 1
    for (int it = 0; it < 4; ++it) {
        int node = blockIdx.x * 64 + it * 16 + (threadIdx.x >> 4);
        if (node >= N) return;

        float4 ak = {0,0,0,0}, av = {0,0,0,0};
        const float* xrow = x + (size_t)node * D;

        #pragma unroll
        for (int i = 0; i < D; i += 4) {
            float4 xv = *(const float4*)(xrow + i);
            #pragma unroll
            for (int s = 0; s < 4; ++s) {
                float xs = (&xv.x)[s];
                fma4(ak, xs, *(const float4*)(&sW[0][(i + s) * D + cg]));
                fma4(av, xs, *(const float4*)(&sW[1][(i + s) * D + cg]));
            }
        }
        ak.x += vbk.x; ak.y += vbk.y; ak.z += vbk.z; ak.w += vbk.w;
        av.x += vbv.x; av.y += vbv.y; av.z += vbv.z; av.w += vbv.w;

        uint4 pkv;
        pkv.x = f2bf(ak.x) | (f2bf(av.x) << 16);
        pkv.y = f2bf(ak.y) | (f2bf(av.y) << 16);
        pkv.z = f2bf(ak.z) | (f2bf(av.z) << 16);
        pkv.w = f2bf(ak.w) | (f2bf(av.w) << 16);
        *(uint4*)(kvp + (size_t)node * D + cg) = pkv;
    }
}

__global__ __launch_bounds__(256) void scan_b(int* __restrict__ bsum, int nb)
{
    __shared__ int sh[256];
    int t = threadIdx.x;
    int v = (t < nb) ? bsum[t] : 0;
    sh[t] = v;
    __syncthreads();
    for (int s = 1; s < 256; s <<= 1) {
        int a = (t >= s) ? sh[t - s] : 0;
        __syncthreads();
        sh[t] += a;
        __syncthreads();
    }
    if (t < nb) bsum[t] = sh[t] - v;   // exclusive
}

__global__ __launch_bounds__(256) void scan_c(
    const int* __restrict__ cnt, const int* __restrict__ bsum,
    int* __restrict__ row_start, int* __restrict__ cursor, int N, int E)
{
    __shared__ int sh[256];
    int t = threadIdx.x;
    int i = blockIdx.x * 256 + t;
    int v = (i < N) ? cnt[i] : 0;
    sh[t] = v;
    __syncthreads();
    for (int s = 1; s < 256; s <<= 1) {
        int a = (t >= s) ? sh[t - s] : 0;
        __syncthreads();
        sh[t] += a;
        __syncthreads();
    }
    int excl = sh[t] - v + bsum[blockIdx.x];
    if (i < N) { row_start[i] = excl; cursor[i] = excl; }
    if (i == N - 1) row_start[N] = E;
}

// ---------------------------------------------------------------------------
// K5: payload scatter. srcs_s[pos] + ea_s[pos] (bf16 row) in CSR order.
// ---------------------------------------------------------------------------
__global__ __launch_bounds__(256) void csr_scatter(
    const int* __restrict__ ei, const float4* __restrict__ ea4,
    int* __restrict__ cursor, int* __restrict__ srcs_s,
    uint_t* __restrict__ ea_s, int E)
{
    int gid = blockIdx.x * 256 + threadIdx.x;
    if (gid >= E) return;
    int src = ei[gid];
    int dst = ei[E + gid];
    float4 r0 = ea4[(size_t)gid * 4 + 0];
    float4 r1 = ea4[(size_t)gid * 4 + 1];
    float4 r2 = ea4[(size_t)gid * 4 + 2];
    float4 r3 = ea4[(size_t)gid * 4 + 3];
    int pos = atomicAdd(&cursor[dst], 1);
    srcs_s[pos] = src;
    uint4 p0, p1;
    p0.x = f2bf(r0.x) | (f2bf(r0.y) << 16);
    p0.y = f2bf(r0.z) | (f2bf(r0.w) << 16);
    p0.z = f2bf(r1.x) | (f2bf(r1.y) << 16);
    p0.w = f2bf(r1.z) | (f2bf(r1.w) << 16);
    p1.x = f2bf(r2.x) | (f2bf(r2.y) << 16);
    p1.y = f2bf(r2.z) | (f2bf(r2.w) << 16);
    p1.z = f2bf(r3.x) | (f2bf(r3.y) << 16);
    p1.w = f2bf(r3.z) | (f2bf(r3.w) << 16);
    *(uint4*)(ea_s + (size_t)pos * 8)     = p0;
    *(uint4*)(ea_s + (size_t)pos * 8 + 4) = p1;
}

// ---------------------------------------------------------------------------
// K6: pull gather. wave = dst node, lane = column. srcs/ea sequential;
//     only kvp is a random gather (12.8MB, L2/L3-resident).
// ---------------------------------------------------------------------------
__global__ __launch_bounds__(256) void node_gather(
    const int*   __restrict__ row_start, // [N+1]
    const int*   __restrict__ srcs_s,    // [E] CSR-ordered src
    const uint_t* __restrict__ ea_s,     // [E*8] CSR-ordered bf16x2
    const float* __restrict__ We, const float* __restrict__ be,
    const float* __restrict__ q, const uint_t* __restrict__ kvp,
    const float* __restrict__ xr,
    const uint_t* __restrict__ Ap, const float* __restrict__ qbe,
    const float* __restrict__ Wbeta,
    float* __restrict__ out, float* __restrict__ S1p, float* __restrict__ S2p,
    int N)
{
    __shared__ float l1[4][D];
    __shared__ float l2[4][D];
    int lane = threadIdx.x & 63;
    int w    = threadIdx.x >> 6;
    int t    = lane & 7;

    float rWe[ED];
    #pragma unroll
    for (int i = 0; i < ED; ++i) rWe[i] = We[i * D + lane];
    float bev = be[lane];
    float wb0 = Wbeta[lane], wb1 = Wbeta[D + lane], wb2 = Wbeta[2 * D + lane];

    float s1bn = 0.f, s2bn = 0.f;
    int stride = gridDim.x * 4;

    for (int nid = blockIdx.x * 4 + w; nid < N; nid += stride) {
        int rs  = row_start[nid];
        int deg = row_start[nid + 1] - rs;

        float  qv   = q[(size_t)nid * D + lane];
        uint_t au   = Ap[(size_t)nid * 64 + lane];
        float  a0   = bf_lo(au), a1 = bf_hi(au);
        float  qbeh = qbe[(size_t)nid * 8 + (lane >> 3)];

        float acc = 0.f, den = 0.f, s0 = 0.f, s1 = 0.f;

        int srcv = 0;
        if (lane < deg) srcv = srcs_s[rs + lane];

        int nb = (deg < 64) ? deg : 64;
        for (int j0 = 0; j0 < nb; j0 += 4) {
            int m = nb - j0; if (m > 4) m = 4;
            uint_t eald = ea_s[(size_t)(rs + j0) * 8 + (lane & 31)];
            uint_t kvu[4];
            #pragma unroll
            for (int j = 0; j < 4; ++j) {
                int jj = (j < m) ? (j0 + j) : j0;
                int s  = __builtin_amdgcn_readlane(srcv, jj);
                kvu[j] = kvp[(size_t)s * D + lane];
            }
            #pragma unroll
            for (int j = 0; j < 4; ++j) {
                if (j < m) {
                    uint_t eau = __shfl(eald, j * 8 + t);
                    float kf = bf_lo(kvu[j]), vf = bf_hi(kvu[j]);
                    float ex = bf_lo(eau), ey = bf_hi(eau);
                    float c = qv * kf + ex * a0 + ey * a1;
                    c += __shfl_xor(c, 1);
                    c += __shfl_xor(c, 2);
                    c += __shfl_xor(c, 4);
                    float p = __expf(c + qbeh);
                    acc += p * vf;
                    den += p;
                    s0  += p * ex;
                    s1  += p * ey;
                }
            }
        }
        // rare fallback: degree > 64
        for (int j = 64; j < deg; ++j) {
            int s = srcs_s[rs + j];
            uint_t kvu = kvp[(size_t)s * D + lane];
            uint_t eau = ea_s[(size_t)(rs + j) * 8 + t];
            float kf = bf_lo(kvu), vf = bf_hi(kvu);
            float ex = bf_lo(eau), ey = bf_hi(eau);
            float c = qv * kf + ex * a0 + ey * a1;
            c += __shfl_xor(c, 1);
            c += __shfl_xor(c, 2);
            c += __shfl_xor(c, 4);
            float p = __expf(c + qbeh);
            acc += p * vf; den += p;
            s0 += p * ex; s1 += p * ey;
        }

        // recombine e-side V: esum_l = sum_i We[i,l]*s[h,i]
        float esum = 0.f;
        #pragma unroll
        for (int i = 0; i < ED; ++i) {
            int srcl = (lane & 56) + (i >> 1);
            float sv = (i & 1) ? __shfl(s1, srcl) : __shfl(s0, srcl);
            esum += sv * rWe[i];
        }

        float o   = (acc + esum + bev * den) / (den + 1e-16f);
        float xrv = xr[(size_t)nid * D + lane];
        float tb  = o * wb0 + xrv * wb1 + (o - xrv) * wb2;
        #pragma unroll
        for (int s = 1; s < 64; s <<= 1) tb += __shfl_xor(tb, s);
        float g  = 1.f / (1.f + __expf(-tb));
        float o2 = g * xrv + (1.f - g) * o;
        out[(size_t)nid * D + lane] = o2;
        s1bn += o2; s2bn += o2 * o2;
    }

    l1[w][lane] = s1bn; l2[w][lane] = s2bn;
    __syncthreads();
    if (threadIdx.x < D) {
        float a = l1[0][threadIdx.x] + l1[1][threadIdx.x]
                + l1[2][threadIdx.x] + l1[3][threadIdx.x];
        float b = l2[0][threadIdx.x] + l2[1][threadIdx.x]
                + l2[2][threadIdx.x] + l2[3][threadIdx.x];
        unsafeAtomicAdd(&S1p[threadIdx.x * 64], a);
        unsafeAtomicAdd(&S2p[threadIdx.x * 64], b);
    }
}

// ---------------------------------------------------------------------------
// K7: batchnorm finalize + apply + LeakyReLU, float4 in place on d_out.
// ---------------------------------------------------------------------------
__global__ __launch_bounds__(256) void bn_apply(
    float4* __restrict__ out, const float* __restrict__ S1p,
    const float* __restrict__ S2p, const float* __restrict__ gamma,
    const float* __restrict__ beta, int total4, float invN)
{
    int gid = blockIdx.x * 256 + threadIdx.x;
    if (gid >= total4) return;
    int col = (gid & 15) * 4;
    float4 g4 = *(const float4*)(gamma + col);
    float4 b4 = *(const float4*)(beta + col);
    float4 y  = out[gid];
    #pragma unroll
    for (int j = 0; j < 4; ++j) {
        float mean = S1p[(col + j) * 64] * invN;
        float var  = S2p[(col + j) * 64] * invN - mean * mean;
        float sc   = (&g4.x)[j] * rsqrtf(var + 1e-5f);
        float sh   = (&b4.x)[j] - mean * sc;
        float tv   = (&y.x)[j] * sc + sh;
        (&y.x)[j]  = (tv >= 0.f) ? tv : 0.01f * tv;
    }
    out[gid] = y;
}

// ---------------------------------------------------------------------------
extern "C" void kernel_launch(void* const* d_in, const int* in_sizes, int n_in,
                              void* d_out, int out_size, void* d_ws, size_t ws_size,
                              hipStream_t stream)
{
    const float* x     = (const float*)d_in[0];
    const int*   ei    = (const int*)  d_in[1];
    const float* ea    = (const float*)d_in[2];
    const float* Wq    = (const float*)d_in[3];
    const float* bq    = (const float*)d_in[4];
    const float* Wk    = (const float*)d_in[5];
    const float* bk    = (const float*)d_in[6];
    const float* Wv    = (const float*)d_in[7];
    const float* bv    = (const float*)d_in[8];
    const float* We    = (const float*)d_in[9];
    const float* be    = (const float*)d_in[10];
    const float* Wskip = (const float*)d_in[11];
    const float* bskip = (const float*)d_in[12];
    const float* Wbeta = (const float*)d_in[13];
    const float* gamma = (const float*)d_in[14];
    const float* betab = (const float*)d_in[15];

    int N = in_sizes[0] / D;   // 50000
    int E = in_sizes[1] / 2;   // 800000

    // ws layout (uint units); total ~82.0 MB
    int*    ws        = (int*)d_ws;
    int*    cnt       = ws;                         // 50000 (also scatter cursor)
    float*  S1p       = (float*)(ws + 50000);       // 4096 padded col sums
    float*  S2p       = (float*)(ws + 54096);       // 4096
    int*    row_start = ws + 58192;                 // 50004
    int*    bsum      = ws + 108240;                // 256 (16B aligned)
    int*    srcs_s    = ws + 108544;                // 800000
    uint_t* ea_s      = (uint_t*)(ws + 908544);     // 6400000
    uint_t* kvp       = (uint_t*)(ws + 7308544);    // 3200000
    float*  q         = (float*)(ws + 10508544);    // 3200000
    float*  xr        = (float*)(ws + 13708544);    // 3200000
    uint_t* Ap        = (uint_t*)(ws + 16908544);   // 3200000
    float*  qbe       = (float*)(ws + 20108544);    // 400000

    // zero cnt + S1p + S2p (contiguous)
    hipMemsetAsync(d_ws, 0, (size_t)58192 * sizeof(int), stream);

    int projB = (N + 63) / 64;      // 782
    int histB = (E + 255) / 256;    // 3125
    proj_qs_hist<<<projB + histB, 256, 0, stream>>>(
        x, Wq, bq, Wskip, bskip, We, be,
        q, xr, Ap, qbe, N, ei, cnt, E, projB);

    int scanB = (N + 255) / 256;    // 196
    proj_kv_scana<<<projB + scanB, 256, 0, stream>>>(
        x, Wk, bk, Wv, bv, kvp, N, projB, cnt, bsum);

    scan_b<<<1, 256, 0, stream>>>(bsum, scanB);
    scan_c<<<scanB, 256, 0, stream>>>(cnt, bsum, row_start, cnt, N, E);

    csr_scatter<<<(E + 255) / 256, 256, 0, stream>>>(
        ei, (const float4*)ea, cnt, srcs_s, ea_s, E);

    node_gather<<<1024, 256, 0, stream>>>(
        row_start, srcs_s, ea_s, We, be, q, kvp, xr, Ap, qbe, Wbeta,
        (float*)d_out, S1p, S2p, N);

    bn_apply<<<(N * 16 + 255) / 256, 256, 0, stream>>>(
        (float4*)d_out, S1p, S2p, gamma, betab, N * 16, 1.0f / (float)N);
}

// Round 10
// 217.649 us; speedup vs baseline: 1.3582x; 1.0398x over previous
//
#include <hip/hip_runtime.h>

#define D   64
#define H   8
#define DH  8
#define ED  16
#define QK_SCALE 0.35355339059327373f   // 1/sqrt(8)

typedef unsigned int uint_t;

__device__ __forceinline__ void fma4(float4& a, float s, const float4& w) {
    a.x += s * w.x; a.y += s * w.y; a.z += s * w.z; a.w += s * w.w;
}
__device__ __forceinline__ uint_t f2bf(float f) {           // RNE f32->bf16
    uint_t u = __float_as_uint(f);
    return (u + 0x7FFFu + ((u >> 16) & 1u)) >> 16;
}
__device__ __forceinline__ float bf_lo(uint_t u) { return __uint_as_float(u << 16); }
__device__ __forceinline__ float bf_hi(uint_t u) { return __uint_as_float(u & 0xFFFF0000u); }

// ---------------------------------------------------------------------------
// K1 fused: [proj_qs blocks | csr_hist blocks]
// ---------------------------------------------------------------------------
__global__ __launch_bounds__(256) void proj_qs_hist(
    const float* __restrict__ x,
    const float* __restrict__ Wq, const float* __restrict__ bq,
    const float* __restrict__ Ws, const float* __restrict__ bs,
    const float* __restrict__ We, const float* __restrict__ be,
    float* __restrict__ q, float* __restrict__ xr,
    uint_t* __restrict__ Ap, float* __restrict__ qbe, int N,
    const int* __restrict__ ei, int* __restrict__ cnt, int E, int projBlocks)
{
    __shared__ float sW[2][D * D];          // 32 KB
    __shared__ float sWe[ED * D];           // 4 KB
    __shared__ float sbe[D];
    if (blockIdx.x >= projBlocks) {
        int gid = (blockIdx.x - projBlocks) * 256 + threadIdx.x;
        if (gid < E) atomicAdd(&cnt[ei[E + gid]], 1);
        return;
    }
    {
        for (int t = threadIdx.x; t < D * D; t += 256) {
            sW[0][t] = Wq[t];
            sW[1][t] = Ws[t];
        }
        for (int t = threadIdx.x; t < ED * D; t += 256) sWe[t] = We[t];
        if (threadIdx.x < D) sbe[threadIdx.x] = be[threadIdx.x];
    }
    __syncthreads();

    int cg = (threadIdx.x & 15) * 4;
    float4 vbq = *(const float4*)(bq + cg);
    float4 vbs = *(const float4*)(bs + cg);
    int h  = cg >> 3;
    int hh = (cg >> 2) & 1;

    #pragma unroll 1
    for (int it = 0; it < 4; ++it) {
        int node = blockIdx.x * 64 + it * 16 + (threadIdx.x >> 4);
        if (node >= N) return;

        float4 aq = {0,0,0,0}, as_ = {0,0,0,0};
        const float* xrow = x + (size_t)node * D;

        #pragma unroll
        for (int i = 0; i < D; i += 4) {
            float4 xv = *(const float4*)(xrow + i);
            #pragma unroll
            for (int s = 0; s < 4; ++s) {
                float xs = (&xv.x)[s];
                fma4(aq,  xs, *(const float4*)(&sW[0][(i + s) * D + cg]));
                fma4(as_, xs, *(const float4*)(&sW[1][(i + s) * D + cg]));
            }
        }
        aq.x = (aq.x + vbq.x) * QK_SCALE;
        aq.y = (aq.y + vbq.y) * QK_SCALE;
        aq.z = (aq.z + vbq.z) * QK_SCALE;
        aq.w = (aq.w + vbq.w) * QK_SCALE;
        as_.x += vbs.x; as_.y += vbs.y; as_.z += vbs.z; as_.w += vbs.w;

        size_t o = (size_t)node * D + cg;
        *(float4*)(q  + o) = aq;
        *(float4*)(xr + o) = as_;

        // --- A projection: A[h,i] = sum_dh q[8h+dh]*We[i,8h+dh] ---
        float part[ED];
        #pragma unroll
        for (int i = 0; i < ED; ++i) {
            float pi = 0.f;
            #pragma unroll
            for (int s = 0; s < 4; ++s)
                pi += (&aq.x)[s] * sWe[i * D + cg + s];
            part[i] = pi;
        }
        float qb = 0.f;
        #pragma unroll
        for (int s = 0; s < 4; ++s) qb += (&aq.x)[s] * sbe[cg + s];
        #pragma unroll
        for (int i = 0; i < ED; ++i) part[i] += __shfl_xor(part[i], 1);
        qb += __shfl_xor(qb, 1);

        uint4 apk;
        apk.x = f2bf(part[hh * 8 + 0]) | (f2bf(part[hh * 8 + 1]) << 16);
        apk.y = f2bf(part[hh * 8 + 2]) | (f2bf(part[hh * 8 + 3]) << 16);
        apk.z = f2bf(part[hh * 8 + 4]) | (f2bf(part[hh * 8 + 5]) << 16);
        apk.w = f2bf(part[hh * 8 + 6]) | (f2bf(part[hh * 8 + 7]) << 16);
        *(uint4*)(Ap + (size_t)node * 64 + h * 8 + hh * 4) = apk;
        if (hh == 0) qbe[(size_t)node * 8 + h] = qb;
    }
}

// ---------------------------------------------------------------------------
// K2 fused: [proj_kv blocks | scan_a blocks]
// ---------------------------------------------------------------------------
__global__ __launch_bounds__(256) void proj_kv_scana(
    const float* __restrict__ x,
    const float* __restrict__ Wk, const float* __restrict__ bk,
    const float* __restrict__ Wv, const float* __restrict__ bv,
    uint_t* __restrict__ kvp, int N, int kvBlocks,
    const int* __restrict__ cnt, int* __restrict__ bsum)
{
    __shared__ float sW[2][D * D];          // 32 KB
    __shared__ int red[256];
    if (blockIdx.x >= kvBlocks) {
        int t = threadIdx.x;
        int i = (blockIdx.x - kvBlocks) * 256 + t;
        red[t] = (i < N) ? cnt[i] : 0;
        __syncthreads();
        for (int s = 128; s > 0; s >>= 1) {
            if (t < s) red[t] += red[t + s];
            __syncthreads();
        }
        if (t == 0) bsum[blockIdx.x - kvBlocks] = red[0];
        return;
    }
    for (int t = threadIdx.x; t < D * D; t += 256) {
        sW[0][t] = Wk[t];
        sW[1][t] = Wv[t];
    }
    __syncthreads();

    int cg = (threadIdx.x & 15) * 4;
    float4 vbk = *(const float4*)(bk + cg);
    float4 vbv = *(const float4*)(bv + cg);

    #pragma unroll 1
    for (int it = 0; it < 4; ++it) {
        int node = blockIdx.x * 64 + it * 16 + (threadIdx.x >> 4);
        if (node >= N) return;

        float4 ak = {0,0,0,0}, av = {0,0,0,0};
        const float* xrow = x + (size_t)node * D;

        #pragma unroll
        for (int i = 0; i < D; i += 4) {
            float4 xv = *(const float4*)(xrow + i);
            #pragma unroll
            for (int s = 0; s < 4; ++s) {
                float xs = (&xv.x)[s];
                fma4(ak, xs, *(const float4*)(&sW[0][(i + s) * D + cg]));
                fma4(av, xs, *(const float4*)(&sW[1][(i + s) * D + cg]));
            }
        }
        ak.x += vbk.x; ak.y += vbk.y; ak.z += vbk.z; ak.w += vbk.w;
        av.x += vbv.x; av.y += vbv.y; av.z += vbv.z; av.w += vbv.w;

        uint4 pkv;
        pkv.x = f2bf(ak.x) | (f2bf(av.x) << 16);
        pkv.y = f2bf(ak.y) | (f2bf(av.y) << 16);
        pkv.z = f2bf(ak.z) | (f2bf(av.z) << 16);
        pkv.w = f2bf(ak.w) | (f2bf(av.w) << 16);
        *(uint4*)(kvp + (size_t)node * D + cg) = pkv;
    }
}

__global__ __launch_bounds__(256) void scan_b(int* __restrict__ bsum, int nb)
{
    __shared__ int sh[256];
    int t = threadIdx.x;
    int v = (t < nb) ? bsum[t] : 0;
    sh[t] = v;
    __syncthreads();
    for (int s = 1; s < 256; s <<= 1) {
        int a = (t >= s) ? sh[t - s] : 0;
        __syncthreads();
        sh[t] += a;
        __syncthreads();
    }
    if (t < nb) bsum[t] = sh[t] - v;   // exclusive
}

__global__ __launch_bounds__(256) void scan_c(
    const int* __restrict__ cnt, const int* __restrict__ bsum,
    int* __restrict__ row_start, int* __restrict__ cursor, int N, int E)
{
    __shared__ int sh[256];
    int t = threadIdx.x;
    int i = blockIdx.x * 256 + t;
    int v = (i < N) ? cnt[i] : 0;
    sh[t] = v;
    __syncthreads();
    for (int s = 1; s < 256; s <<= 1) {
        int a = (t >= s) ? sh[t - s] : 0;
        __syncthreads();
        sh[t] += a;
        __syncthreads();
    }
    int excl = sh[t] - v + bsum[blockIdx.x];
    if (i < N) { row_start[i] = excl; cursor[i] = excl; }
    if (i == N - 1) row_start[N] = E;
}

// ---------------------------------------------------------------------------
// K5: payload scatter. srcs_s[pos] + ea_s[pos] (bf16 row) in CSR order.
// ---------------------------------------------------------------------------
__global__ __launch_bounds__(256) void csr_scatter(
    const int* __restrict__ ei, const float4* __restrict__ ea4,
    int* __restrict__ cursor, int* __restrict__ srcs_s,
    uint_t* __restrict__ ea_s, int E)
{
    int gid = blockIdx.x * 256 + threadIdx.x;
    if (gid >= E) return;
    int src = ei[gid];
    int dst = ei[E + gid];
    float4 r0 = ea4[(size_t)gid * 4 + 0];
    float4 r1 = ea4[(size_t)gid * 4 + 1];
    float4 r2 = ea4[(size_t)gid * 4 + 2];
    float4 r3 = ea4[(size_t)gid * 4 + 3];
    int pos = atomicAdd(&cursor[dst], 1);
    srcs_s[pos] = src;
    uint4 p0, p1;
    p0.x = f2bf(r0.x) | (f2bf(r0.y) << 16);
    p0.y = f2bf(r0.z) | (f2bf(r0.w) << 16);
    p0.z = f2bf(r1.x) | (f2bf(r1.y) << 16);
    p0.w = f2bf(r1.z) | (f2bf(r1.w) << 16);
    p1.x = f2bf(r2.x) | (f2bf(r2.y) << 16);
    p1.y = f2bf(r2.z) | (f2bf(r2.w) << 16);
    p1.z = f2bf(r3.x) | (f2bf(r3.y) << 16);
    p1.w = f2bf(r3.z) | (f2bf(r3.w) << 16);
    *(uint4*)(ea_s + (size_t)pos * 8)     = p0;
    *(uint4*)(ea_s + (size_t)pos * 8 + 4) = p1;
}

// ---------------------------------------------------------------------------
// K6: pull gather, (edge-slot x head) lane layout.
//     lane = e*8+h: 8 edges/batch, each lane owns head h of edge e.
//     No per-edge cross-lane ops; 1 exp per lane per batch; uint4 gathers.
//     Node-end: butterfly reduce over e-lanes, bpermute to lane=col layout.
// ---------------------------------------------------------------------------
__global__ __launch_bounds__(256, 4) void node_gather(
    const int*   __restrict__ row_start, // [N+1]
    const int*   __restrict__ srcs_s,    // [E] CSR-ordered src
    const uint_t* __restrict__ ea_s,     // [E*8] CSR-ordered bf16x2
    const float* __restrict__ We, const float* __restrict__ be,
    const float* __restrict__ q, const uint_t* __restrict__ kvp,
    const float* __restrict__ xr,
    const uint_t* __restrict__ Ap, const float* __restrict__ qbe,
    const float* __restrict__ Wbeta,
    float* __restrict__ out, float* __restrict__ S1p, float* __restrict__ S2p,
    int N)
{
    __shared__ float l1[4][D];
    __shared__ float l2[4][D];
    int lane = threadIdx.x & 63;
    int w    = threadIdx.x >> 6;
    int h    = lane & 7;             // head owned by this lane (mixed layout)
    int e    = lane >> 3;            // edge slot within batch
    int cmix = h * 8 + e;            // this lane's output column (mixed layout)
    int perm = (h << 3) | e;         // == cmix; self-inverse lane permutation

    float rWe[ED];
    #pragma unroll
    for (int i = 0; i < ED; ++i) rWe[i] = We[i * D + cmix];
    float bev = be[cmix];
    // epilogue constants in lane=col layout
    float wb0 = Wbeta[lane], wb1 = Wbeta[D + lane], wb2 = Wbeta[2 * D + lane];

    float s1bn = 0.f, s2bn = 0.f;
    int stride = gridDim.x * 4;

    for (int nid = blockIdx.x * 4 + w; nid < N; nid += stride) {
        int rs  = row_start[nid];
        int deg = row_start[nid + 1] - rs;

        // per-node head data (broadcast across e-lanes)
        const float* qp = q + (size_t)nid * D + h * 8;
        float4 q0 = *(const float4*)qp;
        float4 q1 = *(const float4*)(qp + 4);
        const uint4* app = (const uint4*)(Ap + (size_t)nid * 64 + h * 8);
        uint4 au0 = app[0], au1 = app[1];
        float a16[ED];
        #pragma unroll
        for (int j = 0; j < 4; ++j) {
            a16[(j & 3) * 2]     = bf_lo((&au0.x)[j]);
            a16[(j & 3) * 2 + 1] = bf_hi((&au0.x)[j]);
            a16[8 + (j & 3) * 2]     = bf_lo((&au1.x)[j]);
            a16[8 + (j & 3) * 2 + 1] = bf_hi((&au1.x)[j]);
        }
        float qbeh = qbe[(size_t)nid * 8 + h];

        float acc[8] = {0,0,0,0,0,0,0,0};
        float sv[ED] = {0,0,0,0,0,0,0,0,0,0,0,0,0,0,0,0};
        float den = 0.f;

        for (int j0 = 0; j0 < deg; j0 += 8) {
            int eidx = j0 + e;
            bool valid = eidx < deg;
            int ce = valid ? eidx : 0;
            int src = srcs_s[rs + ce];

            const uint4* kp = (const uint4*)(kvp + (size_t)src * 64 + h * 8);
            uint4 k0 = kp[0], k1 = kp[1];
            const uint4* ep = (const uint4*)(ea_s + (size_t)(rs + ce) * 8);
            uint4 e0 = ep[0], e1 = ep[1];

            float ex[ED];
            #pragma unroll
            for (int j = 0; j < 4; ++j) {
                ex[j * 2]         = bf_lo((&e0.x)[j]);
                ex[j * 2 + 1]     = bf_hi((&e0.x)[j]);
                ex[8 + j * 2]     = bf_lo((&e1.x)[j]);
                ex[8 + j * 2 + 1] = bf_hi((&e1.x)[j]);
            }
            float c = qbeh;
            c += (&q0.x)[0] * bf_lo(k0.x); c += (&q0.x)[1] * bf_lo(k0.y);
            c += (&q0.x)[2] * bf_lo(k0.z); c += (&q0.x)[3] * bf_lo(k0.w);
            c += (&q1.x)[0] * bf_lo(k1.x); c += (&q1.x)[1] * bf_lo(k1.y);
            c += (&q1.x)[2] * bf_lo(k1.z); c += (&q1.x)[3] * bf_lo(k1.w);
            #pragma unroll
            for (int i = 0; i < ED; ++i) c += ex[i] * a16[i];

            float p = valid ? __expf(c) : 0.f;
            den += p;
            acc[0] += p * bf_hi(k0.x); acc[1] += p * bf_hi(k0.y);
            acc[2] += p * bf_hi(k0.z); acc[3] += p * bf_hi(k0.w);
            acc[4] += p * bf_hi(k1.x); acc[5] += p * bf_hi(k1.y);
            acc[6] += p * bf_hi(k1.z); acc[7] += p * bf_hi(k1.w);
            #pragma unroll
            for (int i = 0; i < ED; ++i) sv[i] += p * ex[i];
        }

        // butterfly reduce over e-lanes (xor 8,16,32)
        #pragma unroll
        for (int m = 8; m <= 32; m <<= 1) {
            den += __shfl_xor(den, m);
            #pragma unroll
            for (int i = 0; i < 8; ++i) acc[i] += __shfl_xor(acc[i], m);
            #pragma unroll
            for (int i = 0; i < ED; ++i) sv[i] += __shfl_xor(sv[i], m);
        }
        // select acc[e] -> this lane's column value
        float vsum = acc[0];
        #pragma unroll
        for (int i = 1; i < 8; ++i) vsum = (e == i) ? acc[i] : vsum;
        // e-side recombine for this lane's column
        float esum = 0.f;
        #pragma unroll
        for (int i = 0; i < ED; ++i) esum += rWe[i] * sv[i];

        float o_mix = (vsum + esum + bev * den) / (den + 1e-16f);
        // permute to lane=col layout (self-inverse)
        float o = __shfl(o_mix, perm);

        float xrv = xr[(size_t)nid * D + lane];
        float tb  = o * wb0 + xrv * wb1 + (o - xrv) * wb2;
        #pragma unroll
        for (int s = 1; s < 64; s <<= 1) tb += __shfl_xor(tb, s);
        float g  = 1.f / (1.f + __expf(-tb));
        float o2 = g * xrv + (1.f - g) * o;
        out[(size_t)nid * D + lane] = o2;
        s1bn += o2; s2bn += o2 * o2;
    }

    l1[w][lane] = s1bn; l2[w][lane] = s2bn;
    __syncthreads();
    if (threadIdx.x < D) {
        float a = l1[0][threadIdx.x] + l1[1][threadIdx.x]
                + l1[2][threadIdx.x] + l1[3][threadIdx.x];
        float b = l2[0][threadIdx.x] + l2[1][threadIdx.x]
                + l2[2][threadIdx.x] + l2[3][threadIdx.x];
        unsafeAtomicAdd(&S1p[threadIdx.x * 64], a);
        unsafeAtomicAdd(&S2p[threadIdx.x * 64], b);
    }
}

// ---------------------------------------------------------------------------
// K7: batchnorm finalize + apply + LeakyReLU, float4 in place on d_out.
// ---------------------------------------------------------------------------
__global__ __launch_bounds__(256) void bn_apply(
    float4* __restrict__ out, const float* __restrict__ S1p,
    const float* __restrict__ S2p, const float* __restrict__ gamma,
    const float* __restrict__ beta, int total4, float invN)
{
    int gid = blockIdx.x * 256 + threadIdx.x;
    if (gid >= total4) return;
    int col = (gid & 15) * 4;
    float4 g4 = *(const float4*)(gamma + col);
    float4 b4 = *(const float4*)(beta + col);
    float4 y  = out[gid];
    #pragma unroll
    for (int j = 0; j < 4; ++j) {
        float mean = S1p[(col + j) * 64] * invN;
        float var  = S2p[(col + j) * 64] * invN - mean * mean;
        float sc   = (&g4.x)[j] * rsqrtf(var + 1e-5f);
        float sh   = (&b4.x)[j] - mean * sc;
        float tv   = (&y.x)[j] * sc + sh;
        (&y.x)[j]  = (tv >= 0.f) ? tv : 0.01f * tv;
    }
    out[gid] = y;
}

// ---------------------------------------------------------------------------
extern "C" void kernel_launch(void* const* d_in, const int* in_sizes, int n_in,
                              void* d_out, int out_size, void* d_ws, size_t ws_size,
                              hipStream_t stream)
{
    const float* x     = (const float*)d_in[0];
    const int*   ei    = (const int*)  d_in[1];
    const float* ea    = (const float*)d_in[2];
    const float* Wq    = (const float*)d_in[3];
    const float* bq    = (const float*)d_in[4];
    const float* Wk    = (const float*)d_in[5];
    const float* bk    = (const float*)d_in[6];
    const float* Wv    = (const float*)d_in[7];
    const float* bv    = (const float*)d_in[8];
    const float* We    = (const float*)d_in[9];
    const float* be    = (const float*)d_in[10];
    const float* Wskip = (const float*)d_in[11];
    const float* bskip = (const float*)d_in[12];
    const float* Wbeta = (const float*)d_in[13];
    const float* gamma = (const float*)d_in[14];
    const float* betab = (const float*)d_in[15];

    int N = in_sizes[0] / D;   // 50000
    int E = in_sizes[1] / 2;   // 800000

    // ws layout (uint units); total ~82.0 MB
    int*    ws        = (int*)d_ws;
    int*    cnt       = ws;                         // 50000 (also scatter cursor)
    float*  S1p       = (float*)(ws + 50000);       // 4096 padded col sums
    float*  S2p       = (float*)(ws + 54096);       // 4096
    int*    row_start = ws + 58192;                 // 50004
    int*    bsum      = ws + 108240;                // 256 (16B aligned)
    int*    srcs_s    = ws + 108544;                // 800000
    uint_t* ea_s      = (uint_t*)(ws + 908544);     // 6400000
    uint_t* kvp       = (uint_t*)(ws + 7308544);    // 3200000
    float*  q         = (float*)(ws + 10508544);    // 3200000
    float*  xr        = (float*)(ws + 13708544);    // 3200000
    uint_t* Ap        = (uint_t*)(ws + 16908544);   // 3200000
    float*  qbe       = (float*)(ws + 20108544);    // 400000

    // zero cnt + S1p + S2p (contiguous)
    hipMemsetAsync(d_ws, 0, (size_t)58192 * sizeof(int), stream);

    int projB = (N + 63) / 64;      // 782
    int histB = (E + 255) / 256;    // 3125
    proj_qs_hist<<<projB + histB, 256, 0, stream>>>(
        x, Wq, bq, Wskip, bskip, We, be,
        q, xr, Ap, qbe, N, ei, cnt, E, projB);

    int scanB = (N + 255) / 256;    // 196
    proj_kv_scana<<<projB + scanB, 256, 0, stream>>>(
        x, Wk, bk, Wv, bv, kvp, N, projB, cnt, bsum);

    scan_b<<<1, 256, 0, stream>>>(bsum, scanB);
    scan_c<<<scanB, 256, 0, stream>>>(cnt, bsum, row_start, cnt, N, E);

    csr_scatter<<<(E + 255) / 256, 256, 0, stream>>>(
        ei, (const float4*)ea, cnt, srcs_s, ea_s, E);

    node_gather<<<1024, 256, 0, stream>>>(
        row_start, srcs_s, ea_s, We, be, q, kvp, xr, Ap, qbe, Wbeta,
        (float*)d_out, S1p, S2p, N);

    bn_apply<<<(N * 16 + 255) / 256, 256, 0, stream>>>(
        (float4*)d_out, S1p, S2p, gamma, betab, N * 16, 1.0f / (float)N);
}